// Round 2
// baseline (917.220 us; speedup 1.0000x reference)
//
#include <hip/hip_runtime.h>
#include <math.h>

#define RES 128
#define RES2 (RES*RES)
#define RES3 (RES*RES*RES)

__device__ __forceinline__ int brev7(unsigned x){ return (int)(__brev(x) >> 25); }

__device__ __forceinline__ float2 cmul(float2 a, float2 b){
    return make_float2(a.x*b.x - a.y*b.y, a.x*b.y + a.y*b.x);
}

// 128-point radix-2 DIT FFT in LDS. 64 threads, input already bit-rev loaded.
// SIGN = -1 forward, +1 inverse (unscaled).
template<int SIGN>
__device__ __forceinline__ void fft128_stages(float2* buf, int t){
    #pragma unroll
    for (int len = 2; len <= 128; len <<= 1) {
        int half = len >> 1;
        __syncthreads();
        int k = t & (half - 1);
        int i = ((t & ~(half - 1)) << 1) + k;
        int j = i + half;
        float ang = (float)SIGN * (float)M_PI * (float)k / (float)half;
        float s, c;
        sincosf(ang, &s, &c);
        float2 w = make_float2(c, s);
        float2 u = buf[i];
        float2 v = cmul(buf[j], w);
        buf[i] = make_float2(u.x + v.x, u.y + v.y);
        buf[j] = make_float2(u.x - v.x, u.y - v.y);
    }
    __syncthreads();
}

__global__ __launch_bounds__(64) void fft_z_r2c(const float* __restrict__ in,
                                                float2* __restrict__ out){
    __shared__ float2 buf[RES];
    int line = blockIdx.x;
    int t = threadIdx.x;
    const float* p = in + (size_t)line * RES;
    buf[brev7(t)]      = make_float2(p[t], 0.f);
    buf[brev7(t + 64)] = make_float2(p[t + 64], 0.f);
    fft128_stages<-1>(buf, t);
    float2* q = out + (size_t)line * RES;
    q[t]      = buf[t];
    q[t + 64] = buf[t + 64];
}

template<int SIGN>
__global__ __launch_bounds__(64) void fft_c2c(float2* __restrict__ data, int axis){
    __shared__ float2 buf[RES];
    int line = blockIdx.x;
    int t = threadIdx.x;
    int base, stride;
    if (axis == 1) { int x = line >> 7, z = line & 127; base = (x << 14) + z; stride = RES;  }
    else           { int y = line >> 7, z = line & 127; base = (y << 7) + z;  stride = RES2; }
    float2* p = data + base;
    buf[brev7(t)]      = p[(size_t)t * stride];
    buf[brev7(t + 64)] = p[(size_t)(t + 64) * stride];
    fft128_stages<SIGN>(buf, t);
    p[(size_t)t * stride]        = buf[t];
    p[(size_t)(t + 64) * stride] = buf[t + 64];
}

__global__ __launch_bounds__(64) void fft_z_c2r(const float2* __restrict__ in,
                                                float* __restrict__ out){
    __shared__ float2 buf[RES];
    int line = blockIdx.x;
    int t = threadIdx.x;
    const float2* p = in + (size_t)line * RES;
    buf[brev7(t)]      = p[t];
    buf[brev7(t + 64)] = p[t + 64];
    fft128_stages<1>(buf, t);
    const float scale = 1.f / (float)RES3;
    float* q = out + (size_t)line * RES;
    q[t]      = buf[t].x * scale;
    q[t + 64] = buf[t + 64].x * scale;
}

// acc accumulates u_c * Vhat_c; on c==2 also applies g/(usq+eps) * (-i/(2pi)).
__global__ void accum_spectral(const float2* __restrict__ a, float2* __restrict__ acc, int c){
    int idx = blockIdx.x * blockDim.x + threadIdx.x;
    if (idx >= RES3) return;
    int z = idx & 127, y = (idx >> 7) & 127, x = idx >> 14;
    int coord = (c == 0) ? x : ((c == 1) ? y : z);
    float f = (coord < 64) ? (float)coord : (float)(coord - 128);
    float2 v = a[idx];
    float2 r = make_float2(f * v.x, f * v.y);
    if (c == 0) { acc[idx] = r; return; }
    float2 o = acc[idx];
    o.x += r.x; o.y += r.y;
    if (c == 1) { acc[idx] = o; return; }
    float fx = (x < 64) ? (float)x : (float)(x - 128);
    float fy = (y < 64) ? (float)y : (float)(y - 128);
    float fz = (z < 64) ? (float)z : (float)(z - 128);
    float usq = fx*fx + fy*fy + fz*fz;
    const float K = -2.f * (2.f / 128.f) * (2.f / 128.f);  // -2*(SIGMA/RES)^2
    float g = expf(K * usq);
    float s = g / ((usq + 1e-6f) * (2.f * (float)M_PI));
    acc[idx] = make_float2(s * o.y, -s * o.x);
}

__global__ void scatter_kernel(const float* __restrict__ pts, const float* __restrict__ nrm,
                               float* __restrict__ grid, int N){
    int i = blockIdx.x * blockDim.x + threadIdx.x;
    if (i >= N) return;
    float px = pts[3*i],  py = pts[3*i+1], pz = pts[3*i+2];
    float n0 = nrm[3*i],  n1 = nrm[3*i+1], n2 = nrm[3*i+2];
    float prx = px * RES, pry = py * RES, prz = pz * RES;
    float lox = floorf(prx), loy = floorf(pry), loz = floorf(prz);
    int lix = ((int)lox) & 127, liy = ((int)loy) & 127, liz = ((int)loz) & 127;
    int uix = ((int)ceilf(prx)) & 127, uiy = ((int)ceilf(pry)) & 127, uiz = ((int)ceilf(prz)) & 127;
    float fx = prx - lox, fy = pry - loy, fz = prz - loz;
    #pragma unroll
    for (int cx = 0; cx < 2; cx++){
        int ix = cx ? uix : lix;
        float wx = cx ? fx : 1.f - fx;
        #pragma unroll
        for (int cy = 0; cy < 2; cy++){
            int iy = cy ? uiy : liy;
            float wxy = wx * (cy ? fy : 1.f - fy);
            #pragma unroll
            for (int cz = 0; cz < 2; cz++){
                int iz = cz ? uiz : liz;
                float w = wxy * (cz ? fz : 1.f - fz);
                int flat = (ix << 14) + (iy << 7) + iz;
                atomicAdd(&grid[flat],          w * n0);
                atomicAdd(&grid[RES3 + flat],   w * n1);
                atomicAdd(&grid[2*RES3 + flat], w * n2);
            }
        }
    }
}

__global__ void interp_sum(const float* __restrict__ chi, const float* __restrict__ pts,
                           float* __restrict__ sum, int N){
    int i = blockIdx.x * blockDim.x + threadIdx.x;
    float val = 0.f;
    if (i < N){
        float px = pts[3*i], py = pts[3*i+1], pz = pts[3*i+2];
        float prx = px * RES, pry = py * RES, prz = pz * RES;
        float lox = floorf(prx), loy = floorf(pry), loz = floorf(prz);
        int lix = ((int)lox) & 127, liy = ((int)loy) & 127, liz = ((int)loz) & 127;
        int uix = ((int)ceilf(prx)) & 127, uiy = ((int)ceilf(pry)) & 127, uiz = ((int)ceilf(prz)) & 127;
        float fx = prx - lox, fy = pry - loy, fz = prz - loz;
        #pragma unroll
        for (int cx = 0; cx < 2; cx++){
            int ix = cx ? uix : lix;
            float wx = cx ? fx : 1.f - fx;
            #pragma unroll
            for (int cy = 0; cy < 2; cy++){
                int iy = cy ? uiy : liy;
                float wxy = wx * (cy ? fy : 1.f - fy);
                #pragma unroll
                for (int cz = 0; cz < 2; cz++){
                    int iz = cz ? uiz : liz;
                    float w = wxy * (cz ? fz : 1.f - fz);
                    val += w * chi[(ix << 14) + (iy << 7) + iz];
                }
            }
        }
    }
    __shared__ float red[256];
    int tid = threadIdx.x;
    red[tid] = val;
    __syncthreads();
    #pragma unroll
    for (int s2 = 128; s2 > 0; s2 >>= 1){
        if (tid < s2) red[tid] += red[tid + s2];
        __syncthreads();
    }
    if (tid == 0) atomicAdd(sum, red[0]);
}

__global__ void final_scale(const float* __restrict__ chi, const float* __restrict__ sum,
                            float* __restrict__ out, float invN){
    int i = blockIdx.x * blockDim.x + threadIdx.x;
    if (i >= RES3) return;
    float mean = sum[0] * invN;
    float sc = 0.5f / fabsf(chi[0] - mean);
    out[i] = sc * (chi[i] - mean);
}

extern "C" void kernel_launch(void* const* d_in, const int* in_sizes, int n_in,
                              void* d_out, int out_size, void* d_ws, size_t ws_size,
                              hipStream_t stream) {
    const float* points  = (const float*)d_in[0];
    const float* normals = (const float*)d_in[1];
    float* out = (float*)d_out;
    char* ws = (char*)d_ws;

    float*  grid_v = (float*) ws;                                  // 3*RES3 floats
    float2* bufA   = (float2*)(ws + (size_t)3*RES3*4);             // RES3 float2
    float2* acc    = (float2*)(ws + (size_t)3*RES3*4 + (size_t)RES3*8);
    float*  chiP   = (float*) (ws + (size_t)3*RES3*4 + (size_t)2*RES3*8);
    float*  sumb   = (float*) (ws + (size_t)3*RES3*4 + (size_t)2*RES3*8 + (size_t)RES3*4);

    int N = in_sizes[0] / 3;

    hipMemsetAsync(grid_v, 0, (size_t)3*RES3*4, stream);
    hipMemsetAsync(sumb, 0, 16, stream);

    scatter_kernel<<<(N + 255)/256, 256, 0, stream>>>(points, normals, grid_v, N);

    const int NLINES = RES2;  // 16384
    for (int c = 0; c < 3; c++){
        fft_z_r2c<<<NLINES, 64, 0, stream>>>(grid_v + (size_t)c*RES3, bufA);
        fft_c2c<-1><<<NLINES, 64, 0, stream>>>(bufA, 1);  // y axis
        fft_c2c<-1><<<NLINES, 64, 0, stream>>>(bufA, 0);  // x axis
        accum_spectral<<<RES3/256, 256, 0, stream>>>(bufA, acc, c);
    }

    fft_c2c<1><<<NLINES, 64, 0, stream>>>(acc, 0);        // inverse x
    fft_c2c<1><<<NLINES, 64, 0, stream>>>(acc, 1);        // inverse y
    fft_z_c2r<<<NLINES, 64, 0, stream>>>(acc, chiP);      // inverse z + scale

    interp_sum<<<(N + 255)/256, 256, 0, stream>>>(chiP, points, sumb, N);
    final_scale<<<RES3/256, 256, 0, stream>>>(chiP, sumb, out, 1.0f / (float)N);
}

// Round 4
// 509.897 us; speedup vs baseline: 1.7988x; 1.7988x over previous
//
#include <hip/hip_runtime.h>
#include <math.h>

#define RES 128
#define RES2 (RES*RES)
#define RES3 (RES*RES*RES)

__device__ __forceinline__ int brev7(unsigned x){ return (int)(__brev(x) >> 25); }
// storage index (bit-rev order after DIF) -> signed integer frequency
__device__ __forceinline__ float freq_of(int s){ int k = brev7((unsigned)s); return (float)(k < 64 ? k : k - 128); }
__device__ __forceinline__ float2 cmul(float2 a, float2 b){
    return make_float2(a.x*b.x - a.y*b.y, a.x*b.y + a.y*b.x);
}
__device__ __forceinline__ float2 twd(float ang){ float s, c; __sincosf(ang, &s, &c); return make_float2(c, s); }

// Forward DIF radix-2, 128 points across one wave: lane tt holds x[tt] (r0), x[tt+64] (r1).
// Natural input -> bit-reversed-order spectrum (storage index == reg position).
__device__ __forceinline__ void dif128(float2& r0, float2& r1, int tt){
    {   // h = 64 stage, in-lane pair (tt, tt+64)
        float2 a = r0, b = r1;
        r0 = make_float2(a.x + b.x, a.y + b.y);
        float2 d = make_float2(a.x - b.x, a.y - b.y);
        r1 = cmul(d, twd(-(float)M_PI * (float)tt * (1.f/64.f)));
    }
    #pragma unroll
    for (int h = 32; h >= 1; h >>= 1){
        int bit = tt & h;
        int k = tt & (h - 1);
        float2 w = twd(-(float)M_PI * (float)k / (float)h);
        float2 o0 = make_float2(__shfl_xor(r0.x, h), __shfl_xor(r0.y, h));
        float2 o1 = make_float2(__shfl_xor(r1.x, h), __shfl_xor(r1.y, h));
        if (!bit){
            r0.x += o0.x; r0.y += o0.y;
            r1.x += o1.x; r1.y += o1.y;
        } else {
            r0 = cmul(make_float2(o0.x - r0.x, o0.y - r0.y), w);
            r1 = cmul(make_float2(o1.x - r1.x, o1.y - r1.y), w);
        }
    }
}

// Inverse DIT radix-2: bit-reversed-order input -> natural output (unscaled).
__device__ __forceinline__ void dit128(float2& r0, float2& r1, int tt){
    #pragma unroll
    for (int h = 1; h <= 32; h <<= 1){
        int bit = tt & h;
        int k = tt & (h - 1);
        float2 w = twd((float)M_PI * (float)k / (float)h);
        float2 o0 = make_float2(__shfl_xor(r0.x, h), __shfl_xor(r0.y, h));
        float2 o1 = make_float2(__shfl_xor(r1.x, h), __shfl_xor(r1.y, h));
        if (!bit){
            float2 t0 = cmul(o0, w), t1 = cmul(o1, w);
            r0.x += t0.x; r0.y += t0.y;
            r1.x += t1.x; r1.y += t1.y;
        } else {
            float2 t0 = cmul(r0, w), t1 = cmul(r1, w);
            r0 = make_float2(o0.x - t0.x, o0.y - t0.y);
            r1 = make_float2(o1.x - t1.x, o1.y - t1.y);
        }
    }
    {   // h = 64 stage, in-lane
        float2 w = twd((float)M_PI * (float)tt * (1.f/64.f));
        float2 b = cmul(r1, w);
        float2 a = r0;
        r0 = make_float2(a.x + b.x, a.y + b.y);
        r1 = make_float2(a.x - b.x, a.y - b.y);
    }
}

// ---- z axis: contiguous lines, one wave per line, 4 lines per block ----
__global__ __launch_bounds__(256) void fwd_z(const float* __restrict__ in, float2* __restrict__ out){
    int t = threadIdx.x; int wid = t >> 6, tt = t & 63;
    size_t line = (size_t)blockIdx.x * 4 + wid;
    const float* p = in + line * RES;
    float2 r0 = make_float2(p[tt], 0.f);
    float2 r1 = make_float2(p[tt + 64], 0.f);
    dif128(r0, r1, tt);
    float2* q = out + line * RES;
    q[tt] = r0; q[tt + 64] = r1;
}

__global__ __launch_bounds__(256) void inv_z_c2r(const float2* __restrict__ in, float* __restrict__ out){
    int t = threadIdx.x; int wid = t >> 6, tt = t & 63;
    size_t line = (size_t)blockIdx.x * 4 + wid;
    const float2* p = in + line * RES;
    float2 r0 = p[tt], r1 = p[tt + 64];
    dit128(r0, r1, tt);
    const float sc = 1.f / (float)RES3;
    float* q = out + line * RES;
    q[tt] = r0.x * sc; q[tt + 64] = r1.x * sc;
}

// ---- y axis: tile = fixed x, 16 z, all y. 1024 threads, wave w owns column zz=w ----
template<int DIR>  // 0 = forward (DIF), 1 = inverse (DIT)
__global__ __launch_bounds__(1024) void pass_y(float2* __restrict__ data){
    __shared__ float2 tile[16][130];
    int t = threadIdx.x;
    int x = blockIdx.x >> 3, z0 = (blockIdx.x & 7) << 4;
    size_t base = ((size_t)x << 14) + (size_t)z0;
    int y0 = t >> 4, zz = t & 15;
    int y1 = y0 + 64;
    tile[zz][y0] = data[base + ((size_t)y0 << 7) + zz];
    tile[zz][y1] = data[base + ((size_t)y1 << 7) + zz];
    __syncthreads();
    int w = t >> 6, tt = t & 63;
    float2 r0 = tile[w][tt], r1 = tile[w][tt + 64];
    if (DIR == 0) dif128(r0, r1, tt); else dit128(r0, r1, tt);
    tile[w][tt] = r0; tile[w][tt + 64] = r1;
    __syncthreads();
    data[base + ((size_t)y0 << 7) + zz] = tile[zz][y0];
    data[base + ((size_t)y1 << 7) + zz] = tile[zz][y1];
}

// ---- x axis forward + spectral accumulate: acc (+)= f_c * FFT_x(data) ----
__global__ __launch_bounds__(1024) void fwd_x_acc(const float2* __restrict__ data,
                                                  float2* __restrict__ acc, int c){
    __shared__ float2 tile[16][130];
    int t = threadIdx.x;
    int y = blockIdx.x >> 3, z0 = (blockIdx.x & 7) << 4;
    size_t base = ((size_t)y << 7) + (size_t)z0;
    int x0 = t >> 4, zz = t & 15;
    int x1 = x0 + 64;
    tile[zz][x0] = data[base + ((size_t)x0 << 14) + zz];
    tile[zz][x1] = data[base + ((size_t)x1 << 14) + zz];
    __syncthreads();
    int w = t >> 6, tt = t & 63;
    float2 r0 = tile[w][tt], r1 = tile[w][tt + 64];
    dif128(r0, r1, tt);
    float f0, f1;
    if (c == 0)      { f0 = freq_of(tt); f1 = freq_of(tt + 64); }
    else if (c == 1) { f0 = f1 = freq_of(y); }
    else             { f0 = f1 = freq_of(z0 + w); }
    r0.x *= f0; r0.y *= f0; r1.x *= f1; r1.y *= f1;
    tile[w][tt] = r0; tile[w][tt + 64] = r1;
    __syncthreads();
    size_t g0 = base + ((size_t)x0 << 14) + zz;
    size_t g1 = base + ((size_t)x1 << 14) + zz;
    if (c == 0){
        acc[g0] = tile[zz][x0];
        acc[g1] = tile[zz][x1];
    } else {
        float2 a0 = acc[g0], a1 = acc[g1];
        float2 v0 = tile[zz][x0], v1 = tile[zz][x1];
        acc[g0] = make_float2(a0.x + v0.x, a0.y + v0.y);
        acc[g1] = make_float2(a1.x + v1.x, a1.y + v1.y);
    }
}

// ---- x axis inverse, spectral scale fused into load ----
__global__ __launch_bounds__(1024) void inv_x_scale(float2* __restrict__ data){
    __shared__ float2 tile[16][130];
    int t = threadIdx.x;
    int y = blockIdx.x >> 3, z0 = (blockIdx.x & 7) << 4;
    size_t base = ((size_t)y << 7) + (size_t)z0;
    float fy = freq_of(y);
    int x0 = t >> 4, zz = t & 15;
    float fz = freq_of(z0 + zz);
    const float K = -2.f * (2.f/128.f) * (2.f/128.f);  // -2*(SIGMA/RES)^2
    #pragma unroll
    for (int q = 0; q < 2; q++){
        int x = q ? (x0 + 64) : x0;
        float fx = freq_of(x);
        float usq = fx*fx + fy*fy + fz*fz;
        float gs = __expf(K * usq);
        float s = gs / ((usq + 1e-6f) * (2.f * (float)M_PI));
        float2 v = data[base + ((size_t)x << 14) + zz];
        tile[zz][x] = make_float2(s * v.y, -s * v.x);   // (-i * s) * v
    }
    __syncthreads();
    int w = t >> 6, tt = t & 63;
    float2 r0 = tile[w][tt], r1 = tile[w][tt + 64];
    dit128(r0, r1, tt);
    tile[w][tt] = r0; tile[w][tt + 64] = r1;
    __syncthreads();
    int x1 = x0 + 64;
    data[base + ((size_t)x0 << 14) + zz] = tile[zz][x0];
    data[base + ((size_t)x1 << 14) + zz] = tile[zz][x1];
}

// ---- scatter (unchanged) ----
__global__ void scatter_kernel(const float* __restrict__ pts, const float* __restrict__ nrm,
                               float* __restrict__ grid, int N){
    int i = blockIdx.x * blockDim.x + threadIdx.x;
    if (i >= N) return;
    float px = pts[3*i],  py = pts[3*i+1], pz = pts[3*i+2];
    float n0 = nrm[3*i],  n1 = nrm[3*i+1], n2 = nrm[3*i+2];
    float prx = px * RES, pry = py * RES, prz = pz * RES;
    float lox = floorf(prx), loy = floorf(pry), loz = floorf(prz);
    int lix = ((int)lox) & 127, liy = ((int)loy) & 127, liz = ((int)loz) & 127;
    int uix = ((int)ceilf(prx)) & 127, uiy = ((int)ceilf(pry)) & 127, uiz = ((int)ceilf(prz)) & 127;
    float fx = prx - lox, fy = pry - loy, fz = prz - loz;
    #pragma unroll
    for (int cx = 0; cx < 2; cx++){
        int ix = cx ? uix : lix;
        float wx = cx ? fx : 1.f - fx;
        #pragma unroll
        for (int cy = 0; cy < 2; cy++){
            int iy = cy ? uiy : liy;
            float wxy = wx * (cy ? fy : 1.f - fy);
            #pragma unroll
            for (int cz = 0; cz < 2; cz++){
                int iz = cz ? uiz : liz;
                float w = wxy * (cz ? fz : 1.f - fz);
                int flat = (ix << 14) + (iy << 7) + iz;
                atomicAdd(&grid[flat],          w * n0);
                atomicAdd(&grid[RES3 + flat],   w * n1);
                atomicAdd(&grid[2*RES3 + flat], w * n2);
            }
        }
    }
}

__global__ void interp_sum(const float* __restrict__ chi, const float* __restrict__ pts,
                           float* __restrict__ sum, int N){
    int i = blockIdx.x * blockDim.x + threadIdx.x;
    float val = 0.f;
    if (i < N){
        float px = pts[3*i], py = pts[3*i+1], pz = pts[3*i+2];
        float prx = px * RES, pry = py * RES, prz = pz * RES;
        float lox = floorf(prx), loy = floorf(pry), loz = floorf(prz);
        int lix = ((int)lox) & 127, liy = ((int)loy) & 127, liz = ((int)loz) & 127;
        int uix = ((int)ceilf(prx)) & 127, uiy = ((int)ceilf(pry)) & 127, uiz = ((int)ceilf(prz)) & 127;
        float fx = prx - lox, fy = pry - loy, fz = prz - loz;
        #pragma unroll
        for (int cx = 0; cx < 2; cx++){
            int ix = cx ? uix : lix;
            float wx = cx ? fx : 1.f - fx;
            #pragma unroll
            for (int cy = 0; cy < 2; cy++){
                int iy = cy ? uiy : liy;
                float wxy = wx * (cy ? fy : 1.f - fy);
                #pragma unroll
                for (int cz = 0; cz < 2; cz++){
                    int iz = cz ? uiz : liz;
                    float w = wxy * (cz ? fz : 1.f - fz);
                    val += w * chi[(ix << 14) + (iy << 7) + iz];
                }
            }
        }
    }
    __shared__ float red[256];
    int tid = threadIdx.x;
    red[tid] = val;
    __syncthreads();
    #pragma unroll
    for (int s2 = 128; s2 > 0; s2 >>= 1){
        if (tid < s2) red[tid] += red[tid + s2];
        __syncthreads();
    }
    if (tid == 0) atomicAdd(sum, red[0]);
}

__global__ void final_scale(const float* __restrict__ chi, const float* __restrict__ sum,
                            float* __restrict__ out, float invN){
    int i = blockIdx.x * blockDim.x + threadIdx.x;
    if (i >= RES3) return;
    float mean = sum[0] * invN;
    float sc = 0.5f / fabsf(chi[0] - mean);
    out[i] = sc * (chi[i] - mean);
}

extern "C" void kernel_launch(void* const* d_in, const int* in_sizes, int n_in,
                              void* d_out, int out_size, void* d_ws, size_t ws_size,
                              hipStream_t stream) {
    const float* points  = (const float*)d_in[0];
    const float* normals = (const float*)d_in[1];
    float* out = (float*)d_out;
    char* ws = (char*)d_ws;

    float*  grid_v = (float*) ws;                                            // 3*RES3 f32
    float2* bufA   = (float2*)(ws + (size_t)3*RES3*4);                       // RES3 c64
    float2* acc    = (float2*)(ws + (size_t)3*RES3*4 + (size_t)RES3*8);      // RES3 c64
    float*  chiP   = (float*) (ws + (size_t)3*RES3*4 + (size_t)2*RES3*8);    // RES3 f32
    float*  sumb   = (float*) (ws + (size_t)3*RES3*4 + (size_t)2*RES3*8 + (size_t)RES3*4);

    int N = in_sizes[0] / 3;

    hipMemsetAsync(grid_v, 0, (size_t)3*RES3*4, stream);
    hipMemsetAsync(sumb, 0, 16, stream);

    scatter_kernel<<<(N + 255)/256, 256, 0, stream>>>(points, normals, grid_v, N);

    for (int c = 0; c < 3; c++){
        fwd_z<<<RES2/4, 256, 0, stream>>>(grid_v + (size_t)c*RES3, bufA);
        pass_y<0><<<1024, 1024, 0, stream>>>(bufA);
        fwd_x_acc<<<1024, 1024, 0, stream>>>(bufA, acc, c);
    }

    inv_x_scale<<<1024, 1024, 0, stream>>>(acc);
    pass_y<1><<<1024, 1024, 0, stream>>>(acc);
    inv_z_c2r<<<RES2/4, 256, 0, stream>>>(acc, chiP);

    interp_sum<<<(N + 255)/256, 256, 0, stream>>>(chiP, points, sumb, N);
    final_scale<<<RES3/256, 256, 0, stream>>>(chiP, sumb, out, 1.0f / (float)N);
}

// Round 6
// 286.395 us; speedup vs baseline: 3.2026x; 1.7804x over previous
//
#include <hip/hip_runtime.h>
#include <math.h>

#define RES 128
#define RES2 (RES*RES)
#define RES3 (RES*RES*RES)
#define NROWS 16384   // 128*128 (x,y) row bins

__device__ __forceinline__ int brev7(unsigned x){ return (int)(__brev(x) >> 25); }
// storage index (bit-rev order after DIF) -> signed integer frequency
__device__ __forceinline__ float freq_of(int s){ int k = brev7((unsigned)s); return (float)(k < 64 ? k : k - 128); }
__device__ __forceinline__ float2 cmul(float2 a, float2 b){
    return make_float2(a.x*b.x - a.y*b.y, a.x*b.y + a.y*b.x);
}
__device__ __forceinline__ float2 twd(float ang){ float s, c; __sincosf(ang, &s, &c); return make_float2(c, s); }

// Forward DIF radix-2, 128 points across one wave: lane tt holds x[tt] (r0), x[tt+64] (r1).
__device__ __forceinline__ void dif128(float2& r0, float2& r1, int tt){
    {   // h = 64 stage, in-lane pair (tt, tt+64)
        float2 a = r0, b = r1;
        r0 = make_float2(a.x + b.x, a.y + b.y);
        float2 d = make_float2(a.x - b.x, a.y - b.y);
        r1 = cmul(d, twd(-(float)M_PI * (float)tt * (1.f/64.f)));
    }
    #pragma unroll
    for (int h = 32; h >= 1; h >>= 1){
        int bit = tt & h;
        int k = tt & (h - 1);
        float2 w = twd(-(float)M_PI * (float)k / (float)h);
        float2 o0 = make_float2(__shfl_xor(r0.x, h), __shfl_xor(r0.y, h));
        float2 o1 = make_float2(__shfl_xor(r1.x, h), __shfl_xor(r1.y, h));
        if (!bit){
            r0.x += o0.x; r0.y += o0.y;
            r1.x += o1.x; r1.y += o1.y;
        } else {
            r0 = cmul(make_float2(o0.x - r0.x, o0.y - r0.y), w);
            r1 = cmul(make_float2(o1.x - r1.x, o1.y - r1.y), w);
        }
    }
}

// Inverse DIT radix-2: bit-reversed-order input -> natural output (unscaled).
__device__ __forceinline__ void dit128(float2& r0, float2& r1, int tt){
    #pragma unroll
    for (int h = 1; h <= 32; h <<= 1){
        int bit = tt & h;
        int k = tt & (h - 1);
        float2 w = twd((float)M_PI * (float)k / (float)h);
        float2 o0 = make_float2(__shfl_xor(r0.x, h), __shfl_xor(r0.y, h));
        float2 o1 = make_float2(__shfl_xor(r1.x, h), __shfl_xor(r1.y, h));
        if (!bit){
            float2 t0 = cmul(o0, w), t1 = cmul(o1, w);
            r0.x += t0.x; r0.y += t0.y;
            r1.x += t1.x; r1.y += t1.y;
        } else {
            float2 t0 = cmul(r0, w), t1 = cmul(r1, w);
            r0 = make_float2(o0.x - t0.x, o0.y - t0.y);
            r1 = make_float2(o1.x - t1.x, o1.y - t1.y);
        }
    }
    {   // h = 64 stage, in-lane
        float2 w = twd((float)M_PI * (float)tt * (1.f/64.f));
        float2 b = cmul(r1, w);
        float2 a = r0;
        r0 = make_float2(a.x + b.x, a.y + b.y);
        r1 = make_float2(a.x - b.x, a.y - b.y);
    }
}

// ---- point binning: histogram over (lx,ly) rows ----
__global__ void hist_kernel(const float* __restrict__ pts, int* __restrict__ counts, int N){
    int i = blockIdx.x * blockDim.x + threadIdx.x;
    if (i >= N) return;
    float prx = pts[3*i] * RES, pry = pts[3*i+1] * RES;
    int lx = ((int)floorf(prx)) & 127, ly = ((int)floorf(pry)) & 127;
    atomicAdd(&counts[(lx << 7) | ly], 1);
}

// single-block exclusive scan over 16384 counts; starts[NROWS] = total
__global__ __launch_bounds__(1024) void rowscan(const int* __restrict__ counts,
                                                int* __restrict__ starts){
    __shared__ int buf[2][1024];
    int t = threadIdx.x;
    int c[16];
    int base = t * 16;
    int s = 0;
    #pragma unroll
    for (int k = 0; k < 16; k++){ c[k] = counts[base + k]; s += c[k]; }
    buf[0][t] = s;
    __syncthreads();
    int cur = 0;
    for (int d = 1; d < 1024; d <<= 1){
        int v = buf[cur][t];
        if (t >= d) v += buf[cur][t - d];
        buf[cur ^ 1][t] = v;
        cur ^= 1;
        __syncthreads();
    }
    int incl = buf[cur][t];
    int run = incl - s;   // exclusive
    #pragma unroll
    for (int k = 0; k < 16; k++){ starts[base + k] = run; run += c[k]; }
    if (t == 1023) starts[NROWS] = incl;
}

// place points into row-sorted order (AoS stride 6: px,py,pz,n0,n1,n2)
__global__ void scatter_sorted(const float* __restrict__ pts, const float* __restrict__ nrm,
                               int* __restrict__ cursors, float* __restrict__ sorted, int N){
    int i = blockIdx.x * blockDim.x + threadIdx.x;
    if (i >= N) return;
    float px = pts[3*i], py = pts[3*i+1], pz = pts[3*i+2];
    int lx = ((int)floorf(px * RES)) & 127, ly = ((int)floorf(py * RES)) & 127;
    int pos = atomicAdd(&cursors[(lx << 7) | ly], 1);
    float* q = sorted + (size_t)pos * 6;
    q[0] = px; q[1] = py; q[2] = pz;
    q[3] = nrm[3*i]; q[4] = nrm[3*i+1]; q[5] = nrm[3*i+2];
}

// ---- gather-based rasterization: block = (x,y) column, thread = z. No atomics. ----
#define GCHUNK 128
__global__ __launch_bounds__(128) void gather_grid(const float* __restrict__ sorted,
                                                   const int* __restrict__ starts,
                                                   float* __restrict__ grid){
    __shared__ float P[GCHUNK * 5];
    int x = blockIdx.x >> 7, y = blockIdx.x & 127;
    int z = threadIdx.x;
    float acc0 = 0.f, acc1 = 0.f, acc2 = 0.f;
    #pragma unroll
    for (int r = 0; r < 4; r++){
        int lx = (r & 2) ? x : (x + 127) & 127;
        int ly = (r & 1) ? y : (y + 127) & 127;
        int row = (lx << 7) | ly;
        int rs = starts[row], re = starts[row + 1];
        for (int s0 = rs; s0 < re; s0 += GCHUNK){
            int cnt = min(GCHUNK, re - s0);
            if (z < cnt){
                const float* q = sorted + (size_t)(s0 + z) * 6;
                float prx = q[0] * RES, pry = q[1] * RES;
                float fx = prx - floorf(prx), fy = pry - floorf(pry);
                float wx = (lx == x) ? (1.f - fx) : fx;
                float wy = (ly == y) ? (1.f - fy) : fy;
                P[z*5+0] = q[2] * RES;   // prz
                P[z*5+1] = wx * wy;
                P[z*5+2] = q[3]; P[z*5+3] = q[4]; P[z*5+4] = q[5];
            }
            __syncthreads();
            for (int j = 0; j < cnt; j++){
                float prz = P[j*5+0];
                float lzf = floorf(prz);
                float fz = prz - lzf;
                int lz = ((int)lzf) & 127;
                int dz = (z - lz) & 127;
                float wz = (dz == 0) ? (1.f - fz) : ((dz == 1) ? fz : 0.f);
                float w = wz * P[j*5+1];
                acc0 += w * P[j*5+2];
                acc1 += w * P[j*5+3];
                acc2 += w * P[j*5+4];
            }
            __syncthreads();
        }
    }
    int cell = (x << 14) | (y << 7) | z;
    grid[cell]            = acc0;
    grid[RES3 + cell]     = acc1;
    grid[2*RES3 + cell]   = acc2;
}

// ---- z axis: contiguous lines, one wave per line, 4 lines per block ----
__global__ __launch_bounds__(256) void fwd_z(const float* __restrict__ in, float2* __restrict__ out){
    int t = threadIdx.x; int wid = t >> 6, tt = t & 63;
    size_t line = (size_t)blockIdx.x * 4 + wid;
    const float* p = in + line * RES;
    float2 r0 = make_float2(p[tt], 0.f);
    float2 r1 = make_float2(p[tt + 64], 0.f);
    dif128(r0, r1, tt);
    float2* q = out + line * RES;
    q[tt] = r0; q[tt + 64] = r1;
}

__global__ __launch_bounds__(256) void inv_z_c2r(const float2* __restrict__ in, float* __restrict__ out){
    int t = threadIdx.x; int wid = t >> 6, tt = t & 63;
    size_t line = (size_t)blockIdx.x * 4 + wid;
    const float2* p = in + line * RES;
    float2 r0 = p[tt], r1 = p[tt + 64];
    dit128(r0, r1, tt);
    const float sc = 1.f / (float)RES3;
    float* q = out + line * RES;
    q[tt] = r0.x * sc; q[tt + 64] = r1.x * sc;
}

// ---- y axis: tile = fixed x, 16 z, all y ----
template<int DIR>
__global__ __launch_bounds__(1024) void pass_y(float2* __restrict__ data){
    __shared__ float2 tile[16][130];
    int t = threadIdx.x;
    int x = blockIdx.x >> 3, z0 = (blockIdx.x & 7) << 4;
    size_t base = ((size_t)x << 14) + (size_t)z0;
    int y0 = t >> 4, zz = t & 15;
    int y1 = y0 + 64;
    tile[zz][y0] = data[base + ((size_t)y0 << 7) + zz];
    tile[zz][y1] = data[base + ((size_t)y1 << 7) + zz];
    __syncthreads();
    int w = t >> 6, tt = t & 63;
    float2 r0 = tile[w][tt], r1 = tile[w][tt + 64];
    if (DIR == 0) dif128(r0, r1, tt); else dit128(r0, r1, tt);
    tile[w][tt] = r0; tile[w][tt + 64] = r1;
    __syncthreads();
    data[base + ((size_t)y0 << 7) + zz] = tile[zz][y0];
    data[base + ((size_t)y1 << 7) + zz] = tile[zz][y1];
}

// ---- x axis forward + spectral accumulate ----
__global__ __launch_bounds__(1024) void fwd_x_acc(const float2* __restrict__ data,
                                                  float2* __restrict__ acc, int c){
    __shared__ float2 tile[16][130];
    int t = threadIdx.x;
    int y = blockIdx.x >> 3, z0 = (blockIdx.x & 7) << 4;
    size_t base = ((size_t)y << 7) + (size_t)z0;
    int x0 = t >> 4, zz = t & 15;
    int x1 = x0 + 64;
    tile[zz][x0] = data[base + ((size_t)x0 << 14) + zz];
    tile[zz][x1] = data[base + ((size_t)x1 << 14) + zz];
    __syncthreads();
    int w = t >> 6, tt = t & 63;
    float2 r0 = tile[w][tt], r1 = tile[w][tt + 64];
    dif128(r0, r1, tt);
    float f0, f1;
    if (c == 0)      { f0 = freq_of(tt); f1 = freq_of(tt + 64); }
    else if (c == 1) { f0 = f1 = freq_of(y); }
    else             { f0 = f1 = freq_of(z0 + w); }
    r0.x *= f0; r0.y *= f0; r1.x *= f1; r1.y *= f1;
    tile[w][tt] = r0; tile[w][tt + 64] = r1;
    __syncthreads();
    size_t g0 = base + ((size_t)x0 << 14) + zz;
    size_t g1 = base + ((size_t)x1 << 14) + zz;
    if (c == 0){
        acc[g0] = tile[zz][x0];
        acc[g1] = tile[zz][x1];
    } else {
        float2 a0 = acc[g0], a1 = acc[g1];
        float2 v0 = tile[zz][x0], v1 = tile[zz][x1];
        acc[g0] = make_float2(a0.x + v0.x, a0.y + v0.y);
        acc[g1] = make_float2(a1.x + v1.x, a1.y + v1.y);
    }
}

// ---- x axis inverse, spectral scale fused into load ----
__global__ __launch_bounds__(1024) void inv_x_scale(float2* __restrict__ data){
    __shared__ float2 tile[16][130];
    int t = threadIdx.x;
    int y = blockIdx.x >> 3, z0 = (blockIdx.x & 7) << 4;
    size_t base = ((size_t)y << 7) + (size_t)z0;
    float fy = freq_of(y);
    int x0 = t >> 4, zz = t & 15;
    float fz = freq_of(z0 + zz);
    const float K = -2.f * (2.f/128.f) * (2.f/128.f);
    #pragma unroll
    for (int q = 0; q < 2; q++){
        int x = q ? (x0 + 64) : x0;
        float fx = freq_of(x);
        float usq = fx*fx + fy*fy + fz*fz;
        float gs = __expf(K * usq);
        float s = gs / ((usq + 1e-6f) * (2.f * (float)M_PI));
        float2 v = data[base + ((size_t)x << 14) + zz];
        tile[zz][x] = make_float2(s * v.y, -s * v.x);
    }
    __syncthreads();
    int w = t >> 6, tt = t & 63;
    float2 r0 = tile[w][tt], r1 = tile[w][tt + 64];
    dit128(r0, r1, tt);
    tile[w][tt] = r0; tile[w][tt + 64] = r1;
    __syncthreads();
    int x1 = x0 + 64;
    data[base + ((size_t)x0 << 14) + zz] = tile[zz][x0];
    data[base + ((size_t)x1 << 14) + zz] = tile[zz][x1];
}

__global__ void interp_sum(const float* __restrict__ chi, const float* __restrict__ pts,
                           float* __restrict__ sum, int N){
    int i = blockIdx.x * blockDim.x + threadIdx.x;
    float val = 0.f;
    if (i < N){
        float px = pts[3*i], py = pts[3*i+1], pz = pts[3*i+2];
        float prx = px * RES, pry = py * RES, prz = pz * RES;
        float lox = floorf(prx), loy = floorf(pry), loz = floorf(prz);
        int lix = ((int)lox) & 127, liy = ((int)loy) & 127, liz = ((int)loz) & 127;
        int uix = ((int)ceilf(prx)) & 127, uiy = ((int)ceilf(pry)) & 127, uiz = ((int)ceilf(prz)) & 127;
        float fx = prx - lox, fy = pry - loy, fz = prz - loz;
        #pragma unroll
        for (int cx = 0; cx < 2; cx++){
            int ix = cx ? uix : lix;
            float wx = cx ? fx : 1.f - fx;
            #pragma unroll
            for (int cy = 0; cy < 2; cy++){
                int iy = cy ? uiy : liy;
                float wxy = wx * (cy ? fy : 1.f - fy);
                #pragma unroll
                for (int cz = 0; cz < 2; cz++){
                    int iz = cz ? uiz : liz;
                    float w = wxy * (cz ? fz : 1.f - fz);
                    val += w * chi[(ix << 14) + (iy << 7) + iz];
                }
            }
        }
    }
    __shared__ float red[256];
    int tid = threadIdx.x;
    red[tid] = val;
    __syncthreads();
    #pragma unroll
    for (int s2 = 128; s2 > 0; s2 >>= 1){
        if (tid < s2) red[tid] += red[tid + s2];
        __syncthreads();
    }
    if (tid == 0) atomicAdd(sum, red[0]);
}

__global__ void final_scale(const float* __restrict__ chi, const float* __restrict__ sum,
                            float* __restrict__ out, float invN){
    int i = blockIdx.x * blockDim.x + threadIdx.x;
    if (i >= RES3) return;
    float mean = sum[0] * invN;
    float sc = 0.5f / fabsf(chi[0] - mean);
    out[i] = sc * (chi[i] - mean);
}

extern "C" void kernel_launch(void* const* d_in, const int* in_sizes, int n_in,
                              void* d_out, int out_size, void* d_ws, size_t ws_size,
                              hipStream_t stream) {
    const float* points  = (const float*)d_in[0];
    const float* normals = (const float*)d_in[1];
    float* out = (float*)d_out;
    char* ws = (char*)d_ws;

    size_t off = 0;
    float*  grid_v = (float*) (ws + off); off += (size_t)3*RES3*4;   // 24 MB
    float2* bufA   = (float2*)(ws + off); off += (size_t)RES3*8;     // 16 MB
    float2* acc    = (float2*)(ws + off); off += (size_t)RES3*8;     // 16 MB
    float*  chiP   = (float*) (ws + off); off += (size_t)RES3*4;     //  8 MB
    float*  sumb   = (float*) (ws + off); off += 64;
    int*    counts = (int*)   (ws + off); off += (size_t)NROWS*4;
    int*    starts = (int*)   (ws + off); off += (size_t)(NROWS+1)*4;
    int*    cursors= (int*)   (ws + off); off += (size_t)NROWS*4;
    float*  sorted = (float*) (ws + off);                            // N*6 floats

    int N = in_sizes[0] / 3;

    hipMemsetAsync(counts, 0, (size_t)NROWS*4, stream);
    hipMemsetAsync(sumb, 0, 16, stream);

    hist_kernel<<<(N + 255)/256, 256, 0, stream>>>(points, counts, N);
    rowscan<<<1, 1024, 0, stream>>>(counts, starts);
    hipMemcpyAsync(cursors, starts, (size_t)NROWS*4, hipMemcpyDeviceToDevice, stream);
    scatter_sorted<<<(N + 255)/256, 256, 0, stream>>>(points, normals, cursors, sorted, N);
    gather_grid<<<NROWS, 128, 0, stream>>>(sorted, starts, grid_v);

    for (int c = 0; c < 3; c++){
        fwd_z<<<RES2/4, 256, 0, stream>>>(grid_v + (size_t)c*RES3, bufA);
        pass_y<0><<<1024, 1024, 0, stream>>>(bufA);
        fwd_x_acc<<<1024, 1024, 0, stream>>>(bufA, acc, c);
    }

    inv_x_scale<<<1024, 1024, 0, stream>>>(acc);
    pass_y<1><<<1024, 1024, 0, stream>>>(acc);
    inv_z_c2r<<<RES2/4, 256, 0, stream>>>(acc, chiP);

    interp_sum<<<(N + 255)/256, 256, 0, stream>>>(chiP, points, sumb, N);
    final_scale<<<RES3/256, 256, 0, stream>>>(chiP, sumb, out, 1.0f / (float)N);
}

// Round 7
// 260.310 us; speedup vs baseline: 3.5236x; 1.1002x over previous
//
#include <hip/hip_runtime.h>
#include <math.h>

#define RES 128
#define RES2 (RES*RES)
#define RES3 (RES*RES*RES)
#define NROWS 16384   // 128*128 (x,y) row bins

__device__ __forceinline__ int brev7(unsigned x){ return (int)(__brev(x) >> 25); }
// storage index (bit-rev order after DIF) -> signed integer frequency
__device__ __forceinline__ float freq_of(int s){ int k = brev7((unsigned)s); return (float)(k < 64 ? k : k - 128); }
__device__ __forceinline__ float2 cmul(float2 a, float2 b){
    return make_float2(a.x*b.x - a.y*b.y, a.x*b.y + a.y*b.x);
}
__device__ __forceinline__ float2 twd(float ang){ float s, c; __sincosf(ang, &s, &c); return make_float2(c, s); }

// Forward DIF radix-2, 128 points across one wave: lane tt holds x[tt] (r0), x[tt+64] (r1).
__device__ __forceinline__ void dif128(float2& r0, float2& r1, int tt){
    {   // h = 64 stage, in-lane pair (tt, tt+64)
        float2 a = r0, b = r1;
        r0 = make_float2(a.x + b.x, a.y + b.y);
        float2 d = make_float2(a.x - b.x, a.y - b.y);
        r1 = cmul(d, twd(-(float)M_PI * (float)tt * (1.f/64.f)));
    }
    #pragma unroll
    for (int h = 32; h >= 1; h >>= 1){
        int bit = tt & h;
        int k = tt & (h - 1);
        float2 w = twd(-(float)M_PI * (float)k / (float)h);
        float2 o0 = make_float2(__shfl_xor(r0.x, h), __shfl_xor(r0.y, h));
        float2 o1 = make_float2(__shfl_xor(r1.x, h), __shfl_xor(r1.y, h));
        if (!bit){
            r0.x += o0.x; r0.y += o0.y;
            r1.x += o1.x; r1.y += o1.y;
        } else {
            r0 = cmul(make_float2(o0.x - r0.x, o0.y - r0.y), w);
            r1 = cmul(make_float2(o1.x - r1.x, o1.y - r1.y), w);
        }
    }
}

// Inverse DIT radix-2: bit-reversed-order input -> natural output (unscaled).
__device__ __forceinline__ void dit128(float2& r0, float2& r1, int tt){
    #pragma unroll
    for (int h = 1; h <= 32; h <<= 1){
        int bit = tt & h;
        int k = tt & (h - 1);
        float2 w = twd((float)M_PI * (float)k / (float)h);
        float2 o0 = make_float2(__shfl_xor(r0.x, h), __shfl_xor(r0.y, h));
        float2 o1 = make_float2(__shfl_xor(r1.x, h), __shfl_xor(r1.y, h));
        if (!bit){
            float2 t0 = cmul(o0, w), t1 = cmul(o1, w);
            r0.x += t0.x; r0.y += t0.y;
            r1.x += t1.x; r1.y += t1.y;
        } else {
            float2 t0 = cmul(r0, w), t1 = cmul(r1, w);
            r0 = make_float2(o0.x - t0.x, o0.y - t0.y);
            r1 = make_float2(o1.x - t1.x, o1.y - t1.y);
        }
    }
    {   // h = 64 stage, in-lane
        float2 w = twd((float)M_PI * (float)tt * (1.f/64.f));
        float2 b = cmul(r1, w);
        float2 a = r0;
        r0 = make_float2(a.x + b.x, a.y + b.y);
        r1 = make_float2(a.x - b.x, a.y - b.y);
    }
}

// ---- point binning: histogram over (lx,ly) rows ----
__global__ void hist_kernel(const float* __restrict__ pts, int* __restrict__ counts, int N){
    int i = blockIdx.x * blockDim.x + threadIdx.x;
    if (i >= N) return;
    float prx = pts[3*i] * RES, pry = pts[3*i+1] * RES;
    int lx = ((int)floorf(prx)) & 127, ly = ((int)floorf(pry)) & 127;
    atomicAdd(&counts[(lx << 7) | ly], 1);
}

// single-block exclusive scan over 16384 counts; starts[NROWS] = total; also fills cursors
__global__ __launch_bounds__(1024) void rowscan(const int* __restrict__ counts,
                                                int* __restrict__ starts,
                                                int* __restrict__ cursors){
    __shared__ int buf[2][1024];
    int t = threadIdx.x;
    int c[16];
    int base = t * 16;
    int s = 0;
    #pragma unroll
    for (int k = 0; k < 16; k++){ c[k] = counts[base + k]; s += c[k]; }
    buf[0][t] = s;
    __syncthreads();
    int cur = 0;
    for (int d = 1; d < 1024; d <<= 1){
        int v = buf[cur][t];
        if (t >= d) v += buf[cur][t - d];
        buf[cur ^ 1][t] = v;
        cur ^= 1;
        __syncthreads();
    }
    int incl = buf[cur][t];
    int run = incl - s;   // exclusive
    #pragma unroll
    for (int k = 0; k < 16; k++){ starts[base + k] = run; cursors[base + k] = run; run += c[k]; }
    if (t == 1023) starts[NROWS] = incl;
}

// place points into row-sorted order (AoS stride 6: px,py,pz,n0,n1,n2)
__global__ void scatter_sorted(const float* __restrict__ pts, const float* __restrict__ nrm,
                               int* __restrict__ cursors, float* __restrict__ sorted, int N){
    int i = blockIdx.x * blockDim.x + threadIdx.x;
    if (i >= N) return;
    float px = pts[3*i], py = pts[3*i+1], pz = pts[3*i+2];
    int lx = ((int)floorf(px * RES)) & 127, ly = ((int)floorf(py * RES)) & 127;
    int pos = atomicAdd(&cursors[(lx << 7) | ly], 1);
    float* q = sorted + (size_t)pos * 6;
    q[0] = px; q[1] = py; q[2] = pz;
    q[3] = nrm[3*i]; q[4] = nrm[3*i+1]; q[5] = nrm[3*i+2];
}

// ---- rasterization v2: block = (x,y) column, LDS-atomic scatter over z. ----
__global__ __launch_bounds__(128) void gather_grid(const float* __restrict__ sorted,
                                                   const int* __restrict__ starts,
                                                   float* __restrict__ grid){
    __shared__ float col[3][RES];
    int x = blockIdx.x >> 7, y = blockIdx.x & 127;
    int t = threadIdx.x;
    col[0][t] = 0.f; col[1][t] = 0.f; col[2][t] = 0.f;
    __syncthreads();
    int xm = (x + 127) & 127, ym = (y + 127) & 127;
    int rowv0 = (xm<<7)|ym, rowv1 = (xm<<7)|y, rowv2 = (x<<7)|ym, rowv3 = (x<<7)|y;
    int rs0 = starts[rowv0], re0 = starts[rowv0+1];
    int rs1 = starts[rowv1], re1 = starts[rowv1+1];
    int rs2 = starts[rowv2], re2 = starts[rowv2+1];
    int rs3 = starts[rowv3], re3 = starts[rowv3+1];
    int p1 = re0 - rs0;
    int p2 = p1 + (re1 - rs1);
    int p3 = p2 + (re2 - rs2);
    int tot = p3 + (re3 - rs3);
    for (int base = 0; base < tot; base += 128){
        int k = base + t;
        if (k < tot){
            int i;
            if      (k < p1) i = rs0 + k;
            else if (k < p2) i = rs1 + (k - p1);
            else if (k < p3) i = rs2 + (k - p2);
            else             i = rs3 + (k - p3);
            const float* q = sorted + (size_t)i * 6;
            float prx = q[0]*RES, pry = q[1]*RES, prz = q[2]*RES;
            float flx = floorf(prx), fly = floorf(pry), flz = floorf(prz);
            float fx = prx - flx, fy = pry - fly, fz = prz - flz;
            int lxp = ((int)flx) & 127, lyp = ((int)fly) & 127, lz = ((int)flz) & 127;
            float wx = (lxp == x) ? (1.f - fx) : fx;
            float wy = (lyp == y) ? (1.f - fy) : fy;
            float wxy = wx * wy;
            float w0 = wxy * (1.f - fz), w1 = wxy * fz;
            int z1 = (lz + 1) & 127;
            float n0 = q[3], n1 = q[4], n2 = q[5];
            atomicAdd(&col[0][lz], w0*n0); atomicAdd(&col[0][z1], w1*n0);
            atomicAdd(&col[1][lz], w0*n1); atomicAdd(&col[1][z1], w1*n1);
            atomicAdd(&col[2][lz], w0*n2); atomicAdd(&col[2][z1], w1*n2);
        }
    }
    __syncthreads();
    int cell = (x << 14) | (y << 7) | t;
    grid[cell]          = col[0][t];
    grid[RES3 + cell]   = col[1][t];
    grid[2*RES3 + cell] = col[2][t];
}

// ---- z axis: contiguous lines, one wave per line, 4 lines per block ----
__global__ __launch_bounds__(256) void fwd_z(const float* __restrict__ in, float2* __restrict__ out){
    int t = threadIdx.x; int wid = t >> 6, tt = t & 63;
    size_t line = (size_t)blockIdx.x * 4 + wid;
    const float* p = in + line * RES;
    float2 r0 = make_float2(p[tt], 0.f);
    float2 r1 = make_float2(p[tt + 64], 0.f);
    dif128(r0, r1, tt);
    float2* q = out + line * RES;
    q[tt] = r0; q[tt + 64] = r1;
}

__global__ __launch_bounds__(256) void inv_z_c2r(const float2* __restrict__ in, float* __restrict__ out){
    int t = threadIdx.x; int wid = t >> 6, tt = t & 63;
    size_t line = (size_t)blockIdx.x * 4 + wid;
    const float2* p = in + line * RES;
    float2 r0 = p[tt], r1 = p[tt + 64];
    dit128(r0, r1, tt);
    const float sc = 1.f / (float)RES3;
    float* q = out + line * RES;
    q[tt] = r0.x * sc; q[tt + 64] = r1.x * sc;
}

// ---- y axis pass. DIR: 0=fwd DIF, 1=inv DIT.
// MODE: 0 = plain write dst; 1 = *freq_of(y-storage reg), write dst; 2 = *freq_of(z), ADD into dst.
template<int DIR, int MODE>
__global__ __launch_bounds__(1024) void pass_y(const float2* __restrict__ src, float2* __restrict__ dst){
    __shared__ float2 tile[16][130];
    int t = threadIdx.x;
    int x = blockIdx.x >> 3, z0 = (blockIdx.x & 7) << 4;
    size_t base = ((size_t)x << 14) + (size_t)z0;
    int y0 = t >> 4, zz = t & 15;
    int y1 = y0 + 64;
    tile[zz][y0] = src[base + ((size_t)y0 << 7) + zz];
    tile[zz][y1] = src[base + ((size_t)y1 << 7) + zz];
    __syncthreads();
    int w = t >> 6, tt = t & 63;
    float2 r0 = tile[w][tt], r1 = tile[w][tt + 64];
    if (DIR == 0) dif128(r0, r1, tt); else dit128(r0, r1, tt);
    if (MODE == 1){
        float f0 = freq_of(tt), f1 = freq_of(tt + 64);
        r0.x *= f0; r0.y *= f0; r1.x *= f1; r1.y *= f1;
    }
    if (MODE == 2){
        float f = freq_of(z0 + w);
        r0.x *= f; r0.y *= f; r1.x *= f; r1.y *= f;
    }
    tile[w][tt] = r0; tile[w][tt + 64] = r1;
    __syncthreads();
    size_t g0 = base + ((size_t)y0 << 7) + zz, g1 = base + ((size_t)y1 << 7) + zz;
    if (MODE == 2){
        float2 a0 = dst[g0], a1 = dst[g1];
        float2 v0 = tile[zz][y0], v1 = tile[zz][y1];
        dst[g0] = make_float2(a0.x + v0.x, a0.y + v0.y);
        dst[g1] = make_float2(a1.x + v1.x, a1.y + v1.y);
    } else {
        dst[g0] = tile[zz][y0];
        dst[g1] = tile[zz][y1];
    }
}

// ---- x mega-pass: fwd-x both buffers, combine f_x*B + A, spectral scale, inverse-x, write bufA ----
__global__ __launch_bounds__(1024) void x_mega(const float2* __restrict__ bufB,  // V0, y-passed
                                               float2* __restrict__ bufA){       // f_y*V1 + f_z*V2, y-passed
    __shared__ float2 tA[16][130];
    __shared__ float2 tB[16][130];
    int t = threadIdx.x;
    int y = blockIdx.x >> 3, z0 = (blockIdx.x & 7) << 4;
    size_t base = ((size_t)y << 7) + (size_t)z0;
    int x0 = t >> 4, zz = t & 15;
    int x1 = x0 + 64;
    size_t g0 = base + ((size_t)x0 << 14) + zz;
    size_t g1 = base + ((size_t)x1 << 14) + zz;
    tA[zz][x0] = bufA[g0]; tA[zz][x1] = bufA[g1];
    tB[zz][x0] = bufB[g0]; tB[zz][x1] = bufB[g1];
    __syncthreads();
    int w = t >> 6, tt = t & 63;
    float2 a0 = tA[w][tt], a1 = tA[w][tt + 64];
    float2 b0 = tB[w][tt], b1 = tB[w][tt + 64];
    dif128(a0, a1, tt);
    dif128(b0, b1, tt);
    float fy = freq_of(y), fz = freq_of(z0 + w);
    float fyz = fy*fy + fz*fz;
    const float K = -2.f * (2.f/128.f) * (2.f/128.f);   // -2*(SIGMA/RES)^2
    {
        float fx = freq_of(tt);
        float vx = a0.x + fx*b0.x, vy = a0.y + fx*b0.y;
        float usq = fx*fx + fyz;
        float s = __expf(K*usq) / ((usq + 1e-6f) * (2.f*(float)M_PI));
        a0 = make_float2(s*vy, -s*vx);
    }
    {
        float fx = freq_of(tt + 64);
        float vx = a1.x + fx*b1.x, vy = a1.y + fx*b1.y;
        float usq = fx*fx + fyz;
        float s = __expf(K*usq) / ((usq + 1e-6f) * (2.f*(float)M_PI));
        a1 = make_float2(s*vy, -s*vx);
    }
    dit128(a0, a1, tt);
    tA[w][tt] = a0; tA[w][tt + 64] = a1;
    __syncthreads();
    bufA[g0] = tA[zz][x0];
    bufA[g1] = tA[zz][x1];
}

__global__ void interp_sum(const float* __restrict__ chi, const float* __restrict__ pts,
                           float* __restrict__ sum, int N){
    int i = blockIdx.x * blockDim.x + threadIdx.x;
    float val = 0.f;
    if (i < N){
        float px = pts[3*i], py = pts[3*i+1], pz = pts[3*i+2];
        float prx = px * RES, pry = py * RES, prz = pz * RES;
        float lox = floorf(prx), loy = floorf(pry), loz = floorf(prz);
        int lix = ((int)lox) & 127, liy = ((int)loy) & 127, liz = ((int)loz) & 127;
        int uix = ((int)ceilf(prx)) & 127, uiy = ((int)ceilf(pry)) & 127, uiz = ((int)ceilf(prz)) & 127;
        float fx = prx - lox, fy = pry - loy, fz = prz - loz;
        #pragma unroll
        for (int cx = 0; cx < 2; cx++){
            int ix = cx ? uix : lix;
            float wx = cx ? fx : 1.f - fx;
            #pragma unroll
            for (int cy = 0; cy < 2; cy++){
                int iy = cy ? uiy : liy;
                float wxy = wx * (cy ? fy : 1.f - fy);
                #pragma unroll
                for (int cz = 0; cz < 2; cz++){
                    int iz = cz ? uiz : liz;
                    float w = wxy * (cz ? fz : 1.f - fz);
                    val += w * chi[(ix << 14) + (iy << 7) + iz];
                }
            }
        }
    }
    __shared__ float red[256];
    int tid = threadIdx.x;
    red[tid] = val;
    __syncthreads();
    #pragma unroll
    for (int s2 = 128; s2 > 0; s2 >>= 1){
        if (tid < s2) red[tid] += red[tid + s2];
        __syncthreads();
    }
    if (tid == 0) atomicAdd(sum, red[0]);
}

__global__ void final_scale(const float* __restrict__ chi, const float* __restrict__ sum,
                            float* __restrict__ out, float invN){
    int i = blockIdx.x * blockDim.x + threadIdx.x;
    if (i >= RES3) return;
    float mean = sum[0] * invN;
    float sc = 0.5f / fabsf(chi[0] - mean);
    out[i] = sc * (chi[i] - mean);
}

extern "C" void kernel_launch(void* const* d_in, const int* in_sizes, int n_in,
                              void* d_out, int out_size, void* d_ws, size_t ws_size,
                              hipStream_t stream) {
    const float* points  = (const float*)d_in[0];
    const float* normals = (const float*)d_in[1];
    float* out = (float*)d_out;
    char* ws = (char*)d_ws;

    size_t off = 0;
    float*  grid_v = (float*) (ws + off); off += (size_t)3*RES3*4;   // 24 MB
    float2* bufA   = (float2*)(ws + off); off += (size_t)RES3*8;     // 16 MB
    float2* bufB   = (float2*)(ws + off); off += (size_t)RES3*8;     // 16 MB
    float*  chiP   = (float*) (ws + off); off += (size_t)RES3*4;     //  8 MB
    float*  sumb   = (float*) (ws + off); off += 64;
    int*    counts = (int*)   (ws + off); off += (size_t)NROWS*4;
    int*    starts = (int*)   (ws + off); off += (size_t)(NROWS+1)*4;
    int*    cursors= (int*)   (ws + off); off += (size_t)NROWS*4;
    float*  sorted = (float*) (ws + off);                            // N*6 floats

    int N = in_sizes[0] / 3;

    hipMemsetAsync(counts, 0, (size_t)NROWS*4, stream);
    hipMemsetAsync(sumb, 0, 16, stream);

    hist_kernel<<<(N + 255)/256, 256, 0, stream>>>(points, counts, N);
    rowscan<<<1, 1024, 0, stream>>>(counts, starts, cursors);
    scatter_sorted<<<(N + 255)/256, 256, 0, stream>>>(points, normals, cursors, sorted, N);
    gather_grid<<<NROWS, 128, 0, stream>>>(sorted, starts, grid_v);

    // forward: z then y per channel; channel multipliers folded into y-pass; sum in bufA
    fwd_z<<<RES2/4, 256, 0, stream>>>(grid_v + (size_t)1*RES3, bufB);      // c1
    pass_y<0,1><<<1024, 1024, 0, stream>>>(bufB, bufA);                    // *f_y -> bufA
    fwd_z<<<RES2/4, 256, 0, stream>>>(grid_v + (size_t)2*RES3, bufB);      // c2
    pass_y<0,2><<<1024, 1024, 0, stream>>>(bufB, bufA);                    // *f_z += bufA
    fwd_z<<<RES2/4, 256, 0, stream>>>(grid_v, bufB);                       // c0
    pass_y<0,0><<<1024, 1024, 0, stream>>>(bufB, bufB);                    // plain, in place

    // fwd-x(A,B) + combine f_x*B + A + spectral scale + inv-x, all in one kernel
    x_mega<<<1024, 1024, 0, stream>>>(bufB, bufA);

    pass_y<1,0><<<1024, 1024, 0, stream>>>(bufA, bufA);                    // inverse y
    inv_z_c2r<<<RES2/4, 256, 0, stream>>>(bufA, chiP);                     // inverse z + scale

    interp_sum<<<(N + 255)/256, 256, 0, stream>>>(chiP, points, sumb, N);
    final_scale<<<RES3/256, 256, 0, stream>>>(chiP, sumb, out, 1.0f / (float)N);
}

// Round 8
// 233.509 us; speedup vs baseline: 3.9280x; 1.1148x over previous
//
#include <hip/hip_runtime.h>
#include <math.h>

#define RES 128
#define RES2 (RES*RES)
#define RES3 (RES*RES*RES)
#define NROWS 16384   // 128*128 (x,y) row bins

__device__ __forceinline__ int brev7(unsigned x){ return (int)(__brev(x) >> 25); }
// storage index (bit-rev order after DIF) -> signed integer frequency
__device__ __forceinline__ float freq_of(int s){ int k = brev7((unsigned)s); return (float)(k < 64 ? k : k - 128); }
__device__ __forceinline__ float2 cmul(float2 a, float2 b){
    return make_float2(a.x*b.x - a.y*b.y, a.x*b.y + a.y*b.x);
}
__device__ __forceinline__ float2 twd(float ang){ float s, c; __sincosf(ang, &s, &c); return make_float2(c, s); }

// Forward DIF radix-2, 128 points across one wave: lane tt holds x[tt] (r0), x[tt+64] (r1).
__device__ __forceinline__ void dif128(float2& r0, float2& r1, int tt){
    {   // h = 64 stage, in-lane pair (tt, tt+64)
        float2 a = r0, b = r1;
        r0 = make_float2(a.x + b.x, a.y + b.y);
        float2 d = make_float2(a.x - b.x, a.y - b.y);
        r1 = cmul(d, twd(-(float)M_PI * (float)tt * (1.f/64.f)));
    }
    #pragma unroll
    for (int h = 32; h >= 1; h >>= 1){
        int bit = tt & h;
        int k = tt & (h - 1);
        float2 w = twd(-(float)M_PI * (float)k / (float)h);
        float2 o0 = make_float2(__shfl_xor(r0.x, h), __shfl_xor(r0.y, h));
        float2 o1 = make_float2(__shfl_xor(r1.x, h), __shfl_xor(r1.y, h));
        if (!bit){
            r0.x += o0.x; r0.y += o0.y;
            r1.x += o1.x; r1.y += o1.y;
        } else {
            r0 = cmul(make_float2(o0.x - r0.x, o0.y - r0.y), w);
            r1 = cmul(make_float2(o1.x - r1.x, o1.y - r1.y), w);
        }
    }
}

// Inverse DIT radix-2: bit-reversed-order input -> natural output (unscaled).
__device__ __forceinline__ void dit128(float2& r0, float2& r1, int tt){
    #pragma unroll
    for (int h = 1; h <= 32; h <<= 1){
        int bit = tt & h;
        int k = tt & (h - 1);
        float2 w = twd((float)M_PI * (float)k / (float)h);
        float2 o0 = make_float2(__shfl_xor(r0.x, h), __shfl_xor(r0.y, h));
        float2 o1 = make_float2(__shfl_xor(r1.x, h), __shfl_xor(r1.y, h));
        if (!bit){
            float2 t0 = cmul(o0, w), t1 = cmul(o1, w);
            r0.x += t0.x; r0.y += t0.y;
            r1.x += t1.x; r1.y += t1.y;
        } else {
            float2 t0 = cmul(r0, w), t1 = cmul(r1, w);
            r0 = make_float2(o0.x - t0.x, o0.y - t0.y);
            r1 = make_float2(o1.x - t1.x, o1.y - t1.y);
        }
    }
    {   // h = 64 stage, in-lane
        float2 w = twd((float)M_PI * (float)tt * (1.f/64.f));
        float2 b = cmul(r1, w);
        float2 a = r0;
        r0 = make_float2(a.x + b.x, a.y + b.y);
        r1 = make_float2(a.x - b.x, a.y - b.y);
    }
}

// ---- point binning: histogram over (lx,ly) rows ----
__global__ void hist_kernel(const float* __restrict__ pts, int* __restrict__ counts, int N){
    int i = blockIdx.x * blockDim.x + threadIdx.x;
    if (i >= N) return;
    float prx = pts[3*i] * RES, pry = pts[3*i+1] * RES;
    int lx = ((int)floorf(prx)) & 127, ly = ((int)floorf(pry)) & 127;
    atomicAdd(&counts[(lx << 7) | ly], 1);
}

// single-block exclusive scan over 16384 counts; starts[NROWS] = total; also fills cursors
__global__ __launch_bounds__(1024) void rowscan(const int* __restrict__ counts,
                                                int* __restrict__ starts,
                                                int* __restrict__ cursors){
    __shared__ int buf[2][1024];
    int t = threadIdx.x;
    int c[16];
    int base = t * 16;
    int s = 0;
    #pragma unroll
    for (int k = 0; k < 16; k++){ c[k] = counts[base + k]; s += c[k]; }
    buf[0][t] = s;
    __syncthreads();
    int cur = 0;
    for (int d = 1; d < 1024; d <<= 1){
        int v = buf[cur][t];
        if (t >= d) v += buf[cur][t - d];
        buf[cur ^ 1][t] = v;
        cur ^= 1;
        __syncthreads();
    }
    int incl = buf[cur][t];
    int run = incl - s;   // exclusive
    #pragma unroll
    for (int k = 0; k < 16; k++){ starts[base + k] = run; cursors[base + k] = run; run += c[k]; }
    if (t == 1023) starts[NROWS] = incl;
}

// place points into row-sorted order (AoS stride 6: px,py,pz,n0,n1,n2)
__global__ void scatter_sorted(const float* __restrict__ pts, const float* __restrict__ nrm,
                               int* __restrict__ cursors, float* __restrict__ sorted, int N){
    int i = blockIdx.x * blockDim.x + threadIdx.x;
    if (i >= N) return;
    float px = pts[3*i], py = pts[3*i+1], pz = pts[3*i+2];
    int lx = ((int)floorf(px * RES)) & 127, ly = ((int)floorf(py * RES)) & 127;
    int pos = atomicAdd(&cursors[(lx << 7) | ly], 1);
    float* q = sorted + (size_t)pos * 6;
    q[0] = px; q[1] = py; q[2] = pz;
    q[3] = nrm[3*i]; q[4] = nrm[3*i+1]; q[5] = nrm[3*i+2];
}

// ---- rasterize (x,y) column via LDS atomics, then z-forward-FFT all 3 channels.
// 192 threads = 3 waves; wave c transforms channel c. Writes complex z-spectra.
__global__ __launch_bounds__(192) void gather_z(const float* __restrict__ sorted,
                                                const int* __restrict__ starts,
                                                float2* __restrict__ zF){
    __shared__ float col[3][RES];
    int x = blockIdx.x >> 7, y = blockIdx.x & 127;
    int t = threadIdx.x;
    ((float*)col)[t] = 0.f;
    ((float*)col)[t + 192] = 0.f;
    __syncthreads();
    int xm = (x + 127) & 127, ym = (y + 127) & 127;
    int rowv0 = (xm<<7)|ym, rowv1 = (xm<<7)|y, rowv2 = (x<<7)|ym, rowv3 = (x<<7)|y;
    int rs0 = starts[rowv0], re0 = starts[rowv0+1];
    int rs1 = starts[rowv1], re1 = starts[rowv1+1];
    int rs2 = starts[rowv2], re2 = starts[rowv2+1];
    int rs3 = starts[rowv3], re3 = starts[rowv3+1];
    int p1 = re0 - rs0;
    int p2 = p1 + (re1 - rs1);
    int p3 = p2 + (re2 - rs2);
    int tot = p3 + (re3 - rs3);
    for (int base = 0; base < tot; base += 192){
        int k = base + t;
        if (k < tot){
            int i;
            if      (k < p1) i = rs0 + k;
            else if (k < p2) i = rs1 + (k - p1);
            else if (k < p3) i = rs2 + (k - p2);
            else             i = rs3 + (k - p3);
            const float* q = sorted + (size_t)i * 6;
            float prx = q[0]*RES, pry = q[1]*RES, prz = q[2]*RES;
            float flx = floorf(prx), fly = floorf(pry), flz = floorf(prz);
            float fx = prx - flx, fy = pry - fly, fz = prz - flz;
            int lxp = ((int)flx) & 127, lyp = ((int)fly) & 127, lz = ((int)flz) & 127;
            float wx = (lxp == x) ? (1.f - fx) : fx;
            float wy = (lyp == y) ? (1.f - fy) : fy;
            float wxy = wx * wy;
            float w0 = wxy * (1.f - fz), w1 = wxy * fz;
            int z1 = (lz + 1) & 127;
            atomicAdd(&col[0][lz], w0*q[3]); atomicAdd(&col[0][z1], w1*q[3]);
            atomicAdd(&col[1][lz], w0*q[4]); atomicAdd(&col[1][z1], w1*q[4]);
            atomicAdd(&col[2][lz], w0*q[5]); atomicAdd(&col[2][z1], w1*q[5]);
        }
    }
    __syncthreads();
    int w = t >> 6, tt = t & 63;
    float2 r0 = make_float2(col[w][tt], 0.f);
    float2 r1 = make_float2(col[w][tt + 64], 0.f);
    dif128(r0, r1, tt);
    float2* q = zF + (size_t)w * RES3 + (((size_t)x << 14) | ((size_t)y << 7));
    q[tt] = r0; q[tt + 64] = r1;
}

// ---- all-channel y pass: bufA = f_y*Y(V1) + f_z*Y(V2); bufB = Y(V0) ----
__global__ __launch_bounds__(1024) void mega_y(const float2* __restrict__ zF,
                                               float2* __restrict__ bufA,
                                               float2* __restrict__ bufB){
    __shared__ float2 tile[16][130];
    int t = threadIdx.x;
    int x = blockIdx.x >> 3, z0 = (blockIdx.x & 7) << 4;
    size_t base = ((size_t)x << 14) + (size_t)z0;
    int y0 = t >> 4, zz = t & 15, y1 = y0 + 64;
    size_t i0 = base + ((size_t)y0 << 7) + zz;
    size_t i1 = base + ((size_t)y1 << 7) + zz;
    int w = t >> 6, tt = t & 63;
    // c1: * f_y
    tile[zz][y0] = zF[RES3 + i0]; tile[zz][y1] = zF[RES3 + i1];
    __syncthreads();
    float2 A0 = tile[w][tt], A1 = tile[w][tt + 64];
    __syncthreads();
    dif128(A0, A1, tt);
    { float f0 = freq_of(tt), f1 = freq_of(tt + 64);
      A0.x *= f0; A0.y *= f0; A1.x *= f1; A1.y *= f1; }
    // c2: * f_z, accumulate
    tile[zz][y0] = zF[2*(size_t)RES3 + i0]; tile[zz][y1] = zF[2*(size_t)RES3 + i1];
    __syncthreads();
    float2 C0 = tile[w][tt], C1 = tile[w][tt + 64];
    __syncthreads();
    dif128(C0, C1, tt);
    { float fz = freq_of(z0 + w);
      A0.x += fz*C0.x; A0.y += fz*C0.y; A1.x += fz*C1.x; A1.y += fz*C1.y; }
    // c0: plain
    tile[zz][y0] = zF[i0]; tile[zz][y1] = zF[i1];
    __syncthreads();
    float2 B0 = tile[w][tt], B1 = tile[w][tt + 64];
    __syncthreads();
    dif128(B0, B1, tt);
    // write A
    tile[w][tt] = A0; tile[w][tt + 64] = A1;
    __syncthreads();
    bufA[i0] = tile[zz][y0]; bufA[i1] = tile[zz][y1];
    __syncthreads();
    // write B
    tile[w][tt] = B0; tile[w][tt + 64] = B1;
    __syncthreads();
    bufB[i0] = tile[zz][y0]; bufB[i1] = tile[zz][y1];
}

// ---- x mega-pass: fwd-x both buffers, combine f_x*B + A, spectral scale, inverse-x, write bufA ----
__global__ __launch_bounds__(1024) void x_mega(const float2* __restrict__ bufB,  // V0, y-passed
                                               float2* __restrict__ bufA){       // f_y*V1 + f_z*V2, y-passed
    __shared__ float2 tA[16][130];
    __shared__ float2 tB[16][130];
    int t = threadIdx.x;
    int y = blockIdx.x >> 3, z0 = (blockIdx.x & 7) << 4;
    size_t base = ((size_t)y << 7) + (size_t)z0;
    int x0 = t >> 4, zz = t & 15;
    int x1 = x0 + 64;
    size_t g0 = base + ((size_t)x0 << 14) + zz;
    size_t g1 = base + ((size_t)x1 << 14) + zz;
    tA[zz][x0] = bufA[g0]; tA[zz][x1] = bufA[g1];
    tB[zz][x0] = bufB[g0]; tB[zz][x1] = bufB[g1];
    __syncthreads();
    int w = t >> 6, tt = t & 63;
    float2 a0 = tA[w][tt], a1 = tA[w][tt + 64];
    float2 b0 = tB[w][tt], b1 = tB[w][tt + 64];
    dif128(a0, a1, tt);
    dif128(b0, b1, tt);
    float fy = freq_of(y), fz = freq_of(z0 + w);
    float fyz = fy*fy + fz*fz;
    const float K = -2.f * (2.f/128.f) * (2.f/128.f);   // -2*(SIGMA/RES)^2
    {
        float fx = freq_of(tt);
        float vx = a0.x + fx*b0.x, vy = a0.y + fx*b0.y;
        float usq = fx*fx + fyz;
        float s = __expf(K*usq) / ((usq + 1e-6f) * (2.f*(float)M_PI));
        a0 = make_float2(s*vy, -s*vx);
    }
    {
        float fx = freq_of(tt + 64);
        float vx = a1.x + fx*b1.x, vy = a1.y + fx*b1.y;
        float usq = fx*fx + fyz;
        float s = __expf(K*usq) / ((usq + 1e-6f) * (2.f*(float)M_PI));
        a1 = make_float2(s*vy, -s*vx);
    }
    dit128(a0, a1, tt);
    tA[w][tt] = a0; tA[w][tt + 64] = a1;
    __syncthreads();
    bufA[g0] = tA[zz][x0];
    bufA[g1] = tA[zz][x1];
}

// ---- inverse y pass (plain) ----
__global__ __launch_bounds__(1024) void inv_y(float2* __restrict__ data){
    __shared__ float2 tile[16][130];
    int t = threadIdx.x;
    int x = blockIdx.x >> 3, z0 = (blockIdx.x & 7) << 4;
    size_t base = ((size_t)x << 14) + (size_t)z0;
    int y0 = t >> 4, zz = t & 15, y1 = y0 + 64;
    size_t i0 = base + ((size_t)y0 << 7) + zz;
    size_t i1 = base + ((size_t)y1 << 7) + zz;
    tile[zz][y0] = data[i0]; tile[zz][y1] = data[i1];
    __syncthreads();
    int w = t >> 6, tt = t & 63;
    float2 r0 = tile[w][tt], r1 = tile[w][tt + 64];
    dit128(r0, r1, tt);
    tile[w][tt] = r0; tile[w][tt + 64] = r1;
    __syncthreads();
    data[i0] = tile[zz][y0]; data[i1] = tile[zz][y1];
}

__global__ __launch_bounds__(256) void inv_z_c2r(const float2* __restrict__ in, float* __restrict__ out){
    int t = threadIdx.x; int wid = t >> 6, tt = t & 63;
    size_t line = (size_t)blockIdx.x * 4 + wid;
    const float2* p = in + line * RES;
    float2 r0 = p[tt], r1 = p[tt + 64];
    dit128(r0, r1, tt);
    const float sc = 1.f / (float)RES3;
    float* q = out + line * RES;
    q[tt] = r0.x * sc; q[tt + 64] = r1.x * sc;
}

__global__ void interp_sum(const float* __restrict__ chi, const float* __restrict__ pts,
                           float* __restrict__ sum, int N){
    int i = blockIdx.x * blockDim.x + threadIdx.x;
    float val = 0.f;
    if (i < N){
        float px = pts[3*i], py = pts[3*i+1], pz = pts[3*i+2];
        float prx = px * RES, pry = py * RES, prz = pz * RES;
        float lox = floorf(prx), loy = floorf(pry), loz = floorf(prz);
        int lix = ((int)lox) & 127, liy = ((int)loy) & 127, liz = ((int)loz) & 127;
        int uix = ((int)ceilf(prx)) & 127, uiy = ((int)ceilf(pry)) & 127, uiz = ((int)ceilf(prz)) & 127;
        float fx = prx - lox, fy = pry - loy, fz = prz - loz;
        #pragma unroll
        for (int cx = 0; cx < 2; cx++){
            int ix = cx ? uix : lix;
            float wx = cx ? fx : 1.f - fx;
            #pragma unroll
            for (int cy = 0; cy < 2; cy++){
                int iy = cy ? uiy : liy;
                float wxy = wx * (cy ? fy : 1.f - fy);
                #pragma unroll
                for (int cz = 0; cz < 2; cz++){
                    int iz = cz ? uiz : liz;
                    float w = wxy * (cz ? fz : 1.f - fz);
                    val += w * chi[(ix << 14) + (iy << 7) + iz];
                }
            }
        }
    }
    __shared__ float red[256];
    int tid = threadIdx.x;
    red[tid] = val;
    __syncthreads();
    #pragma unroll
    for (int s2 = 128; s2 > 0; s2 >>= 1){
        if (tid < s2) red[tid] += red[tid + s2];
        __syncthreads();
    }
    if (tid == 0) atomicAdd(sum, red[0]);
}

__global__ void final_scale(const float* __restrict__ chi, const float* __restrict__ sum,
                            float* __restrict__ out, float invN){
    int i = blockIdx.x * blockDim.x + threadIdx.x;
    if (i >= RES3) return;
    float mean = sum[0] * invN;
    float sc = 0.5f / fabsf(chi[0] - mean);
    out[i] = sc * (chi[i] - mean);
}

extern "C" void kernel_launch(void* const* d_in, const int* in_sizes, int n_in,
                              void* d_out, int out_size, void* d_ws, size_t ws_size,
                              hipStream_t stream) {
    const float* points  = (const float*)d_in[0];
    const float* normals = (const float*)d_in[1];
    float* out = (float*)d_out;
    char* ws = (char*)d_ws;

    size_t off = 0;
    float2* zF     = (float2*)(ws + off); off += (size_t)3*RES3*8;   // 48 MB
    float2* bufA   = (float2*)(ws + off); off += (size_t)RES3*8;     // 16 MB
    float2* bufB   = (float2*)(ws + off); off += (size_t)RES3*8;     // 16 MB
    float*  chiP   = (float*) (ws + off); off += (size_t)RES3*4;     //  8 MB
    float*  sumb   = (float*) (ws + off); off += 64;
    int*    counts = (int*)   (ws + off); off += (size_t)NROWS*4;
    int*    starts = (int*)   (ws + off); off += (size_t)(NROWS+1)*4;
    int*    cursors= (int*)   (ws + off); off += (size_t)NROWS*4;
    float*  sorted = (float*) (ws + off);                            // N*6 floats

    int N = in_sizes[0] / 3;

    hipMemsetAsync(counts, 0, (size_t)NROWS*4, stream);
    hipMemsetAsync(sumb, 0, 16, stream);

    hist_kernel<<<(N + 255)/256, 256, 0, stream>>>(points, counts, N);
    rowscan<<<1, 1024, 0, stream>>>(counts, starts, cursors);
    scatter_sorted<<<(N + 255)/256, 256, 0, stream>>>(points, normals, cursors, sorted, N);
    gather_z<<<NROWS, 192, 0, stream>>>(sorted, starts, zF);

    mega_y<<<1024, 1024, 0, stream>>>(zF, bufA, bufB);
    x_mega<<<1024, 1024, 0, stream>>>(bufB, bufA);
    inv_y<<<1024, 1024, 0, stream>>>(bufA);
    inv_z_c2r<<<RES2/4, 256, 0, stream>>>(bufA, chiP);

    interp_sum<<<(N + 255)/256, 256, 0, stream>>>(chiP, points, sumb, N);
    final_scale<<<RES3/256, 256, 0, stream>>>(chiP, sumb, out, 1.0f / (float)N);
}